// Round 9
// baseline (378.655 us; speedup 1.0000x reference)
//
#include <hip/hip_runtime.h>
#include <stdint.h>

#define TT 2048
#define BB 4
#define HH 768
#define NHEADS 4
#define DD 768
#define NN 3072   // NHEADS*DD
#define LL 3
#define BT 8192   // BB*TT
#define KNB 5
#define NBLK 12   // 64-col partial blocks per head (DD/64)
#define ATPB 4    // tokens per attn block (96 threads each, 384/block)

typedef __bf16 bf16x8 __attribute__((ext_vector_type(8)));
typedef float f32x4 __attribute__((ext_vector_type(4)));

__device__ __forceinline__ unsigned short f2bf(float f){
  union { float f; unsigned u; } v; v.f = f;
  unsigned u = v.u;
  return (unsigned short)((u + 0x7FFFu + ((u >> 16) & 1u)) >> 16);
}
__device__ __forceinline__ float bf2f(unsigned short h){
  union { unsigned u; float f; } v; v.u = ((unsigned)h) << 16;
  return v.f;
}
// async global->LDS, 16B per lane; LDS dest = wave-uniform base + lane*16
__device__ __forceinline__ void gload16(const unsigned short* g, unsigned short* l){
  __builtin_amdgcn_global_load_lds((const __attribute__((address_space(1))) void*)g,
                                   (__attribute__((address_space(3))) void*)l, 16, 0, 0);
}

// ---------------- W transpose + bf16 convert: W[l][k][n] fp32 -> Wt[l][n][k] bf16
__global__ void wt_kernel(const float* __restrict__ W, unsigned short* __restrict__ Wt){
  __shared__ float tile[32][33];
  int l = blockIdx.z;
  int n0 = blockIdx.x * 32, k0 = blockIdx.y * 32;
  int tx = threadIdx.x, ty = threadIdx.y; // (32,8)
  const float* Wl = W + (size_t)l * HH * NN;
  for (int r = 0; r < 4; r++)
    tile[ty + r*8][tx] = Wl[(size_t)(k0 + ty + r*8) * NN + n0 + tx];
  __syncthreads();
  unsigned short* Wtl = Wt + (size_t)l * NN * HH;
  for (int r = 0; r < 4; r++){
    int n = n0 + ty + r*8;
    Wtl[(size_t)n * HH + k0 + tx] = f2bf(tile[tx][ty + r*8]);
  }
}

// ---------------- x fp32 -> bf16 (layer 0 GEMM input)
__global__ void xconv_kernel(const float* __restrict__ x, unsigned short* __restrict__ xb){
  int i = blockIdx.x * blockDim.x + threadIdx.x;
  float4 v = ((const float4*)x)[i];
  ushort4 o;
  o.x = f2bf(v.x); o.y = f2bf(v.y); o.z = f2bf(v.z); o.w = f2bf(v.w);
  *(ushort4*)(xb + (size_t)i * 4) = o;
}

// ---------------- GEMM (R6-exact, frozen): BK=64, global_load_lds w=16,
// XOR chunk swizzle, single-buffer 2-barrier K-loop. HIP-level plateau.
#define BM 128
#define BN 128
#define BK 64

__global__ __launch_bounds__(256, 2) void gemm_kernel(
    const unsigned short* __restrict__ xb,
    const unsigned short* __restrict__ wt,
    unsigned short* __restrict__ hout,
    const float* __restrict__ a_srcl,
    const float* __restrict__ a_dstl,
    float* __restrict__ psrc,     // [BT][NHEADS][NBLK]
    float* __restrict__ pdst){
  __shared__ __align__(16) unsigned short xs[BM][BK];   // 16 KB
  __shared__ __align__(16) unsigned short wsd[BN][BK];  // 16 KB
  int bm = blockIdx.y * BM;
  int bn = blockIdx.x * BN;
  int tid = threadIdx.x;
  int wave = tid >> 6, lane = tid & 63;
  int m16 = lane & 15, q = lane >> 4;
  int wm = (wave >> 1) * 64, wn = (wave & 1) * 64;
  int r8 = lane >> 3, c8 = lane & 7;
  int cg = (c8 ^ r8) * 8;     // fetched chunk: position c8 holds global chunk c8^(row&7)
  const unsigned short* ga[4]; const unsigned short* gb[4];
  unsigned short* la[4]; unsigned short* lb[4];
  #pragma unroll
  for (int s = 0; s < 4; s++){
    int row = wave * 32 + s * 8;
    ga[s] = xb + (size_t)(bm + row + r8) * HH + cg;
    gb[s] = wt + (size_t)(bn + row + r8) * HH + cg;
    la[s] = &xs[row][0];
    lb[s] = &wsd[row][0];
  }
  int rd0 = ((0 + q) ^ (m16 & 7)) * 8;   // ks=0 fragment chunk offset
  int rd1 = ((4 + q) ^ (m16 & 7)) * 8;   // ks=1
  f32x4 acc[4][4] = {};
  for (int k0 = 0; k0 < HH; k0 += BK){
    #pragma unroll
    for (int s = 0; s < 4; s++){
      gload16(ga[s] + k0, la[s]);
      gload16(gb[s] + k0, lb[s]);
    }
    __syncthreads();
    bf16x8 af[4], bfr[4];
    for (int i = 0; i < 4; i++)
      af[i] = __builtin_bit_cast(bf16x8, *(const uint4*)(&xs[wm + i*16 + m16][rd0]));
    for (int j = 0; j < 4; j++)
      bfr[j] = __builtin_bit_cast(bf16x8, *(const uint4*)(&wsd[wn + j*16 + m16][rd0]));
    for (int i = 0; i < 4; i++)
      for (int j = 0; j < 4; j++)
        acc[i][j] = __builtin_amdgcn_mfma_f32_16x16x32_bf16(af[i], bfr[j], acc[i][j], 0, 0, 0);
    for (int i = 0; i < 4; i++)
      af[i] = __builtin_bit_cast(bf16x8, *(const uint4*)(&xs[wm + i*16 + m16][rd1]));
    for (int j = 0; j < 4; j++)
      bfr[j] = __builtin_bit_cast(bf16x8, *(const uint4*)(&wsd[wn + j*16 + m16][rd1]));
    for (int i = 0; i < 4; i++)
      for (int j = 0; j < 4; j++)
        acc[i][j] = __builtin_amdgcn_mfma_f32_16x16x32_bf16(af[i], bfr[j], acc[i][j], 0, 0, 0);
    __syncthreads();
  }
  // C store (bf16)
  for (int i = 0; i < 4; i++){
    int row0 = bm + wm + i*16 + q*4;
    for (int j = 0; j < 4; j++){
      int col = bn + wn + j*16 + m16;
      unsigned short* hp = hout + (size_t)row0 * NN + col;
      hp[0]            = f2bf(acc[i][j][0]);
      hp[NN]           = f2bf(acc[i][j][1]);
      hp[2*(size_t)NN] = f2bf(acc[i][j][2]);
      hp[3*(size_t)NN] = f2bf(acc[i][j][3]);
    }
  }
  // fused asrc/adst partials: wave covers 64 cols = one (head, blk) slot
  int col0 = bn + wn;
  int head = col0 / DD;
  int blk  = (col0 % DD) >> 6;
  float wsrc[4], wdstw[4];
  for (int j = 0; j < 4; j++){
    int n = col0 + j*16 + m16;
    wsrc[j]  = a_srcl[n];
    wdstw[j] = a_dstl[n];
  }
  for (int i = 0; i < 4; i++){
    for (int reg = 0; reg < 4; reg++){
      float ss = 0.f, dd = 0.f;
      for (int j = 0; j < 4; j++){
        float v = acc[i][j][reg];
        ss += v * wsrc[j];
        dd += v * wdstw[j];
      }
      ss += __shfl_xor(ss, 1, 64); dd += __shfl_xor(dd, 1, 64);
      ss += __shfl_xor(ss, 2, 64); dd += __shfl_xor(dd, 2, 64);
      ss += __shfl_xor(ss, 4, 64); dd += __shfl_xor(dd, 4, 64);
      ss += __shfl_xor(ss, 8, 64); dd += __shfl_xor(dd, 8, 64);
      if (m16 == 0){
        int row = bm + wm + i*16 + q*4 + reg;
        size_t slot = (size_t)row * (NHEADS * NBLK) + head * NBLK + blk;
        psrc[slot] = ss;
        pdst[slot] = dd;
      }
    }
  }
}

// ---------------- reduce partials -> asrc/adst
__global__ __launch_bounds__(256) void srcred_kernel(
    const float* __restrict__ psrc, const float* __restrict__ pdst,
    float* __restrict__ asrc, float* __restrict__ adst){
  int task = blockIdx.x * 256 + threadIdx.x;   // row*NHEADS + head
  const float* ps = psrc + (size_t)task * NBLK;
  const float* pd = pdst + (size_t)task * NBLK;
  float ss = 0.f, dd = 0.f;
  for (int i = 0; i < NBLK; i++){ ss += ps[i]; dd += pd[i]; }
  asrc[task] = ss;
  adst[task] = dd;
}

// ---------------- attention + head-mean + bias + residual + layernorm
// R9: no h staging. 384 threads = 4 tokens x 96 chunks; each thread reads its
// 20 uint4 h chunks from global (L2-resident), computes its token's softmax
// scores redundantly in-registers (no LDS, no score barrier). LDS only for
// the LN reduction (~3.5 KB) -> occupancy VGPR-bound, loads pipeline.
__global__ __launch_bounds__(384) void attn_ln_kernel(const unsigned short* __restrict__ h,
    const float* __restrict__ asrc, const float* __restrict__ adst,
    const float* __restrict__ xin_f32,          // non-null => layer 0 residual (fp32)
    const unsigned short* __restrict__ xin_bf,  // else residual from bf16 xb
    const float* __restrict__ bias_l,
    const float* __restrict__ gamma_l, const float* __restrict__ beta_l,
    float* __restrict__ x_out, unsigned short* __restrict__ xb_next,
    int write_f32){
  int bid = blockIdx.x;                       // 2048
  int grp = ((bid & 7) << 8) | (bid >> 3);    // XCD-contiguous groups
  int token0 = grp * ATPB;
  int tid = threadIdx.x;
  int wave = tid >> 6, lane = tid & 63;
  int ti = tid / 96, c = tid % 96;            // token-in-block, 8-elem chunk
  int token = token0 + ti;
  int t = token & (TT - 1);
  int bseq = token >> 11;
  __shared__ float part_s[ATPB * 96], part_q[ATPB * 96];
  __shared__ float mv_mean[ATPB], mv_rstd[ATPB];
  // ---- per-thread scores (redundant across the 96 chunk-threads of a token)
  float4 adv = *(const float4*)&adst[token * NHEADS];
  float sc[KNB][NHEADS];
  const unsigned short* rowp[KNB];
  #pragma unroll
  for (int k = 0; k < KNB; k++){
    int tn = t + k - 2;
    int tnc = min(max(tn, 0), TT - 1);
    rowp[k] = h + ((size_t)(bseq * TT + tnc)) * NN + c * 8;
    float4 sv = *(const float4*)&asrc[(bseq * TT + tnc) * NHEADS];
    bool ok = (tn >= 0) && (tn < TT);
    float* s4 = (float*)&sv;
    float* ad4 = (float*)&adv;
    #pragma unroll
    for (int hd = 0; hd < NHEADS; hd++){
      float s = s4[hd] + ad4[hd];
      s = s > 0.f ? s : 0.2f * s;             // leaky_relu 0.2
      sc[k][hd] = ok ? s : -3.0e38f;
    }
  }
  float ac[NHEADS][KNB];
  #pragma unroll
  for (int hd = 0; hd < NHEADS; hd++){
    float mx = -3.0e38f;
    #pragma unroll
    for (int k = 0; k < KNB; k++) mx = fmaxf(mx, sc[k][hd]);
    float den = 0.f;
    float e[KNB];
    #pragma unroll
    for (int k = 0; k < KNB; k++){
      e[k] = (sc[k][hd] > -1.0e38f) ? __expf(sc[k][hd] - mx) : 0.f;
      den += e[k];
    }
    float inv = 0.25f / den;                  // fold 1/HEADS into attn
    #pragma unroll
    for (int k = 0; k < KNB; k++) ac[hd][k] = e[k] * inv;
  }
  // ---- weighted combine straight from global (L2)
  float y8[8] = {};
  #pragma unroll
  for (int hd = 0; hd < NHEADS; hd++){
    #pragma unroll
    for (int k = 0; k < KNB; k++){
      uint4 u = *(const uint4*)(rowp[k] + hd * DD);
      bf16x8 v = __builtin_bit_cast(bf16x8, u);
      float a = ac[hd][k];
      #pragma unroll
      for (int e = 0; e < 8; e++) y8[e] += a * (float)v[e];
    }
  }
  // ---- bias + residual, LN partial
  float xr[8], bb[8];
  if (xin_f32){
    const float4* p = (const float4*)&xin_f32[(size_t)token * HH + c * 8];
    *(float4*)&xr[0] = p[0]; *(float4*)&xr[4] = p[1];
  } else {
    uint4 u = *(const uint4*)&xin_bf[(size_t)token * HH + c * 8];
    const unsigned short* us = (const unsigned short*)&u;
    #pragma unroll
    for (int e = 0; e < 8; e++) xr[e] = bf2f(us[e]);
  }
  { const float4* p = (const float4*)&bias_l[c * 8];
    *(float4*)&bb[0] = p[0]; *(float4*)&bb[4] = p[1]; }
  float s = 0.f, sq = 0.f;
  #pragma unroll
  for (int e = 0; e < 8; e++){
    float zz = y8[e] + bb[e] + xr[e];
    y8[e] = zz; s += zz; sq += zz * zz;
  }
  part_s[tid] = s; part_q[tid] = sq;
  __syncthreads();
  if (wave < ATPB){
    float vs = part_s[wave * 96 + lane];
    float vq = part_q[wave * 96 + lane];
    if (lane < 32){
      vs += part_s[wave * 96 + 64 + lane];
      vq += part_q[wave * 96 + 64 + lane];
    }
    for (int off = 32; off > 0; off >>= 1){
      vs += __shfl_xor(vs, off, 64);
      vq += __shfl_xor(vq, off, 64);
    }
    if (lane == 0){
      float mean = vs * (1.f / HH);
      float var = vq * (1.f / HH) - mean * mean;
      mv_mean[wave] = mean;
      mv_rstd[wave] = rsqrtf(var + 1e-5f);
    }
  }
  __syncthreads();
  float mean = mv_mean[ti], rstd = mv_rstd[ti];
  float gr[8], br[8];
  { const float4* p = (const float4*)&gamma_l[c * 8];
    *(float4*)&gr[0] = p[0]; *(float4*)&gr[4] = p[1]; }
  { const float4* p = (const float4*)&beta_l[c * 8];
    *(float4*)&br[0] = p[0]; *(float4*)&br[4] = p[1]; }
  float o[8];
  #pragma unroll
  for (int e = 0; e < 8; e++)
    o[e] = (y8[e] - mean) * rstd * gr[e] + br[e];
  if (write_f32){
    float* xo = &x_out[(size_t)token * HH + c * 8];
    *(float4*)&xo[0] = *(float4*)&o[0];
    *(float4*)&xo[4] = *(float4*)&o[4];
  } else {
    unsigned short o16[8];
    #pragma unroll
    for (int e = 0; e < 8; e++) o16[e] = f2bf(o[e]);
    *(uint4*)(&xb_next[(size_t)token * HH + c * 8]) = *(uint4*)&o16[0];
  }
}

extern "C" void kernel_launch(void* const* d_in, const int* in_sizes, int n_in,
                              void* d_out, int out_size, void* d_ws, size_t ws_size,
                              hipStream_t stream) {
  const float* x     = (const float*)d_in[0];
  const float* W     = (const float*)d_in[1];
  const float* a_src = (const float*)d_in[2];
  const float* a_dst = (const float*)d_in[3];
  const float* bias  = (const float*)d_in[4];
  const float* gamma = (const float*)d_in[5];
  const float* beta  = (const float*)d_in[6];
  float* out = (float*)d_out;

  char* ws = (char*)d_ws;
  size_t off = 0;
  auto alloc = [&](size_t bytes)->char*{
    char* p = ws + off;
    off = (off + bytes + 255) & ~(size_t)255;
    return p;
  };
  unsigned short* wt   = (unsigned short*)alloc((size_t)LL * NN * HH * 2);
  unsigned short* xb   = (unsigned short*)alloc((size_t)BT * HH * 2);
  unsigned short* hbuf = (unsigned short*)alloc((size_t)BT * NN * 2);
  float* psrc  = (float*)alloc((size_t)BT * NHEADS * NBLK * 4);
  float* pdst  = (float*)alloc((size_t)BT * NHEADS * NBLK * 4);
  float* asrcb = (float*)alloc((size_t)BT * NHEADS * 4);
  float* adstb = (float*)alloc((size_t)BT * NHEADS * 4);

  wt_kernel<<<dim3(NN/32, HH/32, LL), dim3(32, 8), 0, stream>>>(W, wt);
  xconv_kernel<<<(BT * HH / 4) / 256, 256, 0, stream>>>(x, xb);

  for (int l = 0; l < LL; l++){
    gemm_kernel<<<dim3(NN / BN, BT / BM), 256, 0, stream>>>(
        xb, wt + (size_t)l * NN * HH, hbuf,
        a_src + (size_t)l * NHEADS * DD, a_dst + (size_t)l * NHEADS * DD,
        psrc, pdst);
    srcred_kernel<<<BT * NHEADS / 256, 256, 0, stream>>>(psrc, pdst, asrcb, adstb);
    attn_ln_kernel<<<BT / ATPB, 384, 0, stream>>>(hbuf, asrcb, adstb,
        (l == 0) ? x : nullptr, xb,
        bias + (size_t)l * DD, gamma + (size_t)l * HH, beta + (size_t)l * HH,
        out, xb, (l == LL - 1) ? 1 : 0);
  }
}

// Round 10
// 340.507 us; speedup vs baseline: 1.1120x; 1.1120x over previous
//
#include <hip/hip_runtime.h>
#include <stdint.h>

#define TT 2048
#define BB 4
#define HH 768
#define NHEADS 4
#define DD 768
#define NN 3072   // NHEADS*DD
#define LL 3
#define BT 8192   // BB*TT
#define KNB 5
#define NBLK 12   // 64-col partial blocks per head (DD/64)
#define ATPB 4    // tokens per attn block
#define NROWS 8   // ATPB + KNB - 1 (halo rows staged)

typedef __bf16 bf16x8 __attribute__((ext_vector_type(8)));
typedef float f32x4 __attribute__((ext_vector_type(4)));

__device__ __forceinline__ unsigned short f2bf(float f){
  union { float f; unsigned u; } v; v.f = f;
  unsigned u = v.u;
  return (unsigned short)((u + 0x7FFFu + ((u >> 16) & 1u)) >> 16);
}
__device__ __forceinline__ float bf2f(unsigned short h){
  union { unsigned u; float f; } v; v.u = ((unsigned)h) << 16;
  return v.f;
}
// async global->LDS, 16B per lane; LDS dest = wave-uniform base + lane*16
__device__ __forceinline__ void gload16(const unsigned short* g, unsigned short* l){
  __builtin_amdgcn_global_load_lds((const __attribute__((address_space(1))) void*)g,
                                   (__attribute__((address_space(3))) void*)l, 16, 0, 0);
}

// ---------------- W transpose + bf16 convert: W[l][k][n] fp32 -> Wt[l][n][k] bf16
__global__ void wt_kernel(const float* __restrict__ W, unsigned short* __restrict__ Wt){
  __shared__ float tile[32][33];
  int l = blockIdx.z;
  int n0 = blockIdx.x * 32, k0 = blockIdx.y * 32;
  int tx = threadIdx.x, ty = threadIdx.y; // (32,8)
  const float* Wl = W + (size_t)l * HH * NN;
  for (int r = 0; r < 4; r++)
    tile[ty + r*8][tx] = Wl[(size_t)(k0 + ty + r*8) * NN + n0 + tx];
  __syncthreads();
  unsigned short* Wtl = Wt + (size_t)l * NN * HH;
  for (int r = 0; r < 4; r++){
    int n = n0 + ty + r*8;
    Wtl[(size_t)n * HH + k0 + tx] = f2bf(tile[tx][ty + r*8]);
  }
}

// ---------------- x fp32 -> bf16 (layer 0 GEMM input)
__global__ void xconv_kernel(const float* __restrict__ x, unsigned short* __restrict__ xb){
  int i = blockIdx.x * blockDim.x + threadIdx.x;
  float4 v = ((const float4*)x)[i];
  ushort4 o;
  o.x = f2bf(v.x); o.y = f2bf(v.y); o.z = f2bf(v.z); o.w = f2bf(v.w);
  *(ushort4*)(xb + (size_t)i * 4) = o;
}

// ---------------- GEMM (R6-exact, frozen): BK=64, global_load_lds w=16,
// XOR chunk swizzle, single-buffer 2-barrier K-loop. HIP-level plateau
// (dbuf/pipelining measured worse: R3, R8).
#define BM 128
#define BN 128
#define BK 64

__global__ __launch_bounds__(256, 2) void gemm_kernel(
    const unsigned short* __restrict__ xb,
    const unsigned short* __restrict__ wt,
    unsigned short* __restrict__ hout,
    const float* __restrict__ a_srcl,
    const float* __restrict__ a_dstl,
    float* __restrict__ psrc,     // [BT][NHEADS][NBLK]
    float* __restrict__ pdst){
  __shared__ __align__(16) unsigned short xs[BM][BK];   // 16 KB
  __shared__ __align__(16) unsigned short wsd[BN][BK];  // 16 KB
  int bm = blockIdx.y * BM;
  int bn = blockIdx.x * BN;
  int tid = threadIdx.x;
  int wave = tid >> 6, lane = tid & 63;
  int m16 = lane & 15, q = lane >> 4;
  int wm = (wave >> 1) * 64, wn = (wave & 1) * 64;
  int r8 = lane >> 3, c8 = lane & 7;
  int cg = (c8 ^ r8) * 8;     // fetched chunk: position c8 holds global chunk c8^(row&7)
  const unsigned short* ga[4]; const unsigned short* gb[4];
  unsigned short* la[4]; unsigned short* lb[4];
  #pragma unroll
  for (int s = 0; s < 4; s++){
    int row = wave * 32 + s * 8;
    ga[s] = xb + (size_t)(bm + row + r8) * HH + cg;
    gb[s] = wt + (size_t)(bn + row + r8) * HH + cg;
    la[s] = &xs[row][0];
    lb[s] = &wsd[row][0];
  }
  int rd0 = ((0 + q) ^ (m16 & 7)) * 8;   // ks=0 fragment chunk offset
  int rd1 = ((4 + q) ^ (m16 & 7)) * 8;   // ks=1
  f32x4 acc[4][4] = {};
  for (int k0 = 0; k0 < HH; k0 += BK){
    #pragma unroll
    for (int s = 0; s < 4; s++){
      gload16(ga[s] + k0, la[s]);
      gload16(gb[s] + k0, lb[s]);
    }
    __syncthreads();
    bf16x8 af[4], bfr[4];
    for (int i = 0; i < 4; i++)
      af[i] = __builtin_bit_cast(bf16x8, *(const uint4*)(&xs[wm + i*16 + m16][rd0]));
    for (int j = 0; j < 4; j++)
      bfr[j] = __builtin_bit_cast(bf16x8, *(const uint4*)(&wsd[wn + j*16 + m16][rd0]));
    for (int i = 0; i < 4; i++)
      for (int j = 0; j < 4; j++)
        acc[i][j] = __builtin_amdgcn_mfma_f32_16x16x32_bf16(af[i], bfr[j], acc[i][j], 0, 0, 0);
    for (int i = 0; i < 4; i++)
      af[i] = __builtin_bit_cast(bf16x8, *(const uint4*)(&xs[wm + i*16 + m16][rd1]));
    for (int j = 0; j < 4; j++)
      bfr[j] = __builtin_bit_cast(bf16x8, *(const uint4*)(&wsd[wn + j*16 + m16][rd1]));
    for (int i = 0; i < 4; i++)
      for (int j = 0; j < 4; j++)
        acc[i][j] = __builtin_amdgcn_mfma_f32_16x16x32_bf16(af[i], bfr[j], acc[i][j], 0, 0, 0);
    __syncthreads();
  }
  // C store (bf16)
  for (int i = 0; i < 4; i++){
    int row0 = bm + wm + i*16 + q*4;
    for (int j = 0; j < 4; j++){
      int col = bn + wn + j*16 + m16;
      unsigned short* hp = hout + (size_t)row0 * NN + col;
      hp[0]            = f2bf(acc[i][j][0]);
      hp[NN]           = f2bf(acc[i][j][1]);
      hp[2*(size_t)NN] = f2bf(acc[i][j][2]);
      hp[3*(size_t)NN] = f2bf(acc[i][j][3]);
    }
  }
  // fused asrc/adst partials: wave covers 64 cols = one (head, blk) slot
  int col0 = bn + wn;
  int head = col0 / DD;
  int blk  = (col0 % DD) >> 6;
  float wsrc[4], wdstw[4];
  for (int j = 0; j < 4; j++){
    int n = col0 + j*16 + m16;
    wsrc[j]  = a_srcl[n];
    wdstw[j] = a_dstl[n];
  }
  for (int i = 0; i < 4; i++){
    for (int reg = 0; reg < 4; reg++){
      float ss = 0.f, dd = 0.f;
      for (int j = 0; j < 4; j++){
        float v = acc[i][j][reg];
        ss += v * wsrc[j];
        dd += v * wdstw[j];
      }
      ss += __shfl_xor(ss, 1, 64); dd += __shfl_xor(dd, 1, 64);
      ss += __shfl_xor(ss, 2, 64); dd += __shfl_xor(dd, 2, 64);
      ss += __shfl_xor(ss, 4, 64); dd += __shfl_xor(dd, 4, 64);
      ss += __shfl_xor(ss, 8, 64); dd += __shfl_xor(dd, 8, 64);
      if (m16 == 0){
        int row = bm + wm + i*16 + q*4 + reg;
        size_t slot = (size_t)row * (NHEADS * NBLK) + head * NBLK + blk;
        psrc[slot] = ss;
        pdst[slot] = dd;
      }
    }
  }
}

// ---------------- attention + head-mean + bias + residual + layernorm
// R6-exact staged structure (best measured attn variant) + srcred fused:
// block sums the 12-float psrc/pdst partials for its 8 halo tokens x 4 heads
// into LDS (64 threads, L2-resident reads), then softmax reads LDS.
__global__ __launch_bounds__(384) void attn_ln_kernel(const unsigned short* __restrict__ h,
    const float* __restrict__ psrc, const float* __restrict__ pdst,
    const float* __restrict__ xin_f32,          // non-null => layer 0 residual (fp32)
    const unsigned short* __restrict__ xin_bf,  // else residual from bf16 xb
    const float* __restrict__ bias_l,
    const float* __restrict__ gamma_l, const float* __restrict__ beta_l,
    float* __restrict__ x_out, unsigned short* __restrict__ xb_next,
    int write_f32){
  int bid = blockIdx.x;                       // 2048
  int grp = ((bid & 7) << 8) | (bid >> 3);    // XCD-contiguous groups
  int token0 = grp * ATPB;
  int t0 = token0 & (TT - 1);
  int bseq = token0 >> 11;
  int tid = threadIdx.x;
  int wave = tid >> 6, lane = tid & 63;
  __shared__ __align__(16) unsigned short hs[NROWS][NN];   // 48 KB
  __shared__ float attn_s[ATPB][NHEADS][KNB];
  __shared__ float as_sh[NROWS * NHEADS], ad_sh[NROWS * NHEADS];
  __shared__ float part_s[ATPB * 96], part_q[ATPB * 96];
  __shared__ float mv_mean[ATPB], mv_rstd[ATPB];
  // stage 8 clamped rows via async DMA (issues immediately, drains at barrier)
  #pragma unroll
  for (int j = 0; j < NROWS; j++){
    int g = t0 - 2 + j;
    g = min(max(g, 0), TT - 1);
    const unsigned short* src = h + ((size_t)(bseq * TT + g)) * NN + tid * 8;
    gload16(src, &hs[j][wave * 512]);
  }
  // fused srcred: 64 threads sum the halo tokens' partials into LDS
  if (tid < 2 * NROWS * NHEADS){     // 64
    int which = tid >= NROWS * NHEADS;
    int i = tid & (NROWS * NHEADS - 1);
    int lt = i >> 2, head = i & 3;
    int tcl = min(max(t0 - 2 + lt, 0), TT - 1);
    const float* p = (which ? pdst : psrc) +
        ((size_t)(bseq * TT + tcl) * NHEADS + head) * NBLK;
    float4 a = *(const float4*)(p);
    float4 b = *(const float4*)(p + 4);
    float4 d = *(const float4*)(p + 8);
    float s = a.x+a.y+a.z+a.w + b.x+b.y+b.z+b.w + d.x+d.y+d.z+d.w;
    (which ? ad_sh : as_sh)[i] = s;
  }
  __syncthreads();
  if (tid < ATPB * NHEADS){          // 16: per-(token,head) softmax
    int ti = tid >> 2, head = tid & 3;
    int t = t0 + ti;
    float sc[KNB];
    float mx = -3.0e38f;
    float ad = ad_sh[(ti + 2) * NHEADS + head];
    for (int k = 0; k < KNB; k++){
      int tn = t + k - 2;
      if (tn >= 0 && tn < TT){
        float s = as_sh[(ti + k) * NHEADS + head] + ad;
        s = s > 0.f ? s : 0.2f * s;       // leaky_relu 0.2
        sc[k] = s; mx = fmaxf(mx, s);
      } else sc[k] = -3.0e38f;
    }
    float den = 0.f;
    for (int k = 0; k < KNB; k++){
      float e = (sc[k] > -1.0e38f) ? __expf(sc[k] - mx) : 0.f;
      sc[k] = e; den += e;
    }
    float inv = 0.25f / den;              // fold 1/HEADS into attn
    for (int k = 0; k < KNB; k++) attn_s[ti][head][k] = sc[k] * inv;
  }
  __syncthreads();
  int ti = tid / 96, c = tid % 96;        // token-in-block, 8-elem chunk
  int token = token0 + ti;
  float ac[NHEADS][KNB];
  for (int hd = 0; hd < NHEADS; hd++)
    for (int k = 0; k < KNB; k++) ac[hd][k] = attn_s[ti][hd][k];
  float y8[8] = {};
  for (int hd = 0; hd < NHEADS; hd++){
    #pragma unroll
    for (int k = 0; k < KNB; k++){
      bf16x8 v = __builtin_bit_cast(bf16x8, *(const uint4*)(&hs[ti + k][hd * DD + c * 8]));
      float a = ac[hd][k];
      #pragma unroll
      for (int e = 0; e < 8; e++) y8[e] += a * (float)v[e];
    }
  }
  float xr[8], bb[8];
  if (xin_f32){
    const float4* p = (const float4*)&xin_f32[(size_t)token * HH + c * 8];
    *(float4*)&xr[0] = p[0]; *(float4*)&xr[4] = p[1];
  } else {
    uint4 u = *(const uint4*)&xin_bf[(size_t)token * HH + c * 8];
    const unsigned short* us = (const unsigned short*)&u;
    #pragma unroll
    for (int e = 0; e < 8; e++) xr[e] = bf2f(us[e]);
  }
  { const float4* p = (const float4*)&bias_l[c * 8];
    *(float4*)&bb[0] = p[0]; *(float4*)&bb[4] = p[1]; }
  float s = 0.f, sq = 0.f;
  #pragma unroll
  for (int e = 0; e < 8; e++){
    float zz = y8[e] + bb[e] + xr[e];
    y8[e] = zz; s += zz; sq += zz * zz;
  }
  part_s[tid] = s; part_q[tid] = sq;
  __syncthreads();
  if (wave < ATPB){
    float vs = part_s[wave * 96 + lane];
    float vq = part_q[wave * 96 + lane];
    if (lane < 32){
      vs += part_s[wave * 96 + 64 + lane];
      vq += part_q[wave * 96 + 64 + lane];
    }
    for (int off = 32; off > 0; off >>= 1){
      vs += __shfl_xor(vs, off, 64);
      vq += __shfl_xor(vq, off, 64);
    }
    if (lane == 0){
      float mean = vs * (1.f / HH);
      float var = vq * (1.f / HH) - mean * mean;
      mv_mean[wave] = mean;
      mv_rstd[wave] = rsqrtf(var + 1e-5f);
    }
  }
  __syncthreads();
  float mean = mv_mean[ti], rstd = mv_rstd[ti];
  float gr[8], br[8];
  { const float4* p = (const float4*)&gamma_l[c * 8];
    *(float4*)&gr[0] = p[0]; *(float4*)&gr[4] = p[1]; }
  { const float4* p = (const float4*)&beta_l[c * 8];
    *(float4*)&br[0] = p[0]; *(float4*)&br[4] = p[1]; }
  float o[8];
  #pragma unroll
  for (int e = 0; e < 8; e++)
    o[e] = (y8[e] - mean) * rstd * gr[e] + br[e];
  if (write_f32){
    float* xo = &x_out[(size_t)token * HH + c * 8];
    *(float4*)&xo[0] = *(float4*)&o[0];
    *(float4*)&xo[4] = *(float4*)&o[4];
  } else {
    unsigned short o16[8];
    #pragma unroll
    for (int e = 0; e < 8; e++) o16[e] = f2bf(o[e]);
    *(uint4*)(&xb_next[(size_t)token * HH + c * 8]) = *(uint4*)&o16[0];
  }
}

extern "C" void kernel_launch(void* const* d_in, const int* in_sizes, int n_in,
                              void* d_out, int out_size, void* d_ws, size_t ws_size,
                              hipStream_t stream) {
  const float* x     = (const float*)d_in[0];
  const float* W     = (const float*)d_in[1];
  const float* a_src = (const float*)d_in[2];
  const float* a_dst = (const float*)d_in[3];
  const float* bias  = (const float*)d_in[4];
  const float* gamma = (const float*)d_in[5];
  const float* beta  = (const float*)d_in[6];
  float* out = (float*)d_out;

  char* ws = (char*)d_ws;
  size_t off = 0;
  auto alloc = [&](size_t bytes)->char*{
    char* p = ws + off;
    off = (off + bytes + 255) & ~(size_t)255;
    return p;
  };
  unsigned short* wt   = (unsigned short*)alloc((size_t)LL * NN * HH * 2);
  unsigned short* xb   = (unsigned short*)alloc((size_t)BT * HH * 2);
  unsigned short* hbuf = (unsigned short*)alloc((size_t)BT * NN * 2);
  float* psrc  = (float*)alloc((size_t)BT * NHEADS * NBLK * 4);
  float* pdst  = (float*)alloc((size_t)BT * NHEADS * NBLK * 4);

  wt_kernel<<<dim3(NN/32, HH/32, LL), dim3(32, 8), 0, stream>>>(W, wt);
  xconv_kernel<<<(BT * HH / 4) / 256, 256, 0, stream>>>(x, xb);

  for (int l = 0; l < LL; l++){
    gemm_kernel<<<dim3(NN / BN, BT / BM), 256, 0, stream>>>(
        xb, wt + (size_t)l * NN * HH, hbuf,
        a_src + (size_t)l * NHEADS * DD, a_dst + (size_t)l * NHEADS * DD,
        psrc, pdst);
    attn_ln_kernel<<<BT / ATPB, 384, 0, stream>>>(hbuf, psrc, pdst,
        (l == 0) ? x : nullptr, xb,
        bias + (size_t)l * DD, gamma + (size_t)l * HH, beta + (size_t)l * HH,
        out, xb, (l == LL - 1) ? 1 : 0);
  }
}

// Round 11
// 335.226 us; speedup vs baseline: 1.1296x; 1.0158x over previous
//
#include <hip/hip_runtime.h>
#include <stdint.h>

#define TT 2048
#define BB 4
#define HH 768
#define NHEADS 4
#define DD 768
#define NN 3072   // NHEADS*DD
#define LL 3
#define BT 8192   // BB*TT
#define KNB 5
#define NBLK 12   // 64-col partial blocks per head (DD/64)
#define ATPB 4    // tokens per attn block
#define NROWS 8   // ATPB + KNB - 1 (halo rows staged)

typedef __bf16 bf16x8 __attribute__((ext_vector_type(8)));
typedef float f32x4 __attribute__((ext_vector_type(4)));

__device__ __forceinline__ unsigned short f2bf(float f){
  union { float f; unsigned u; } v; v.f = f;
  unsigned u = v.u;
  return (unsigned short)((u + 0x7FFFu + ((u >> 16) & 1u)) >> 16);
}
__device__ __forceinline__ float bf2f(unsigned short h){
  union { unsigned u; float f; } v; v.u = ((unsigned)h) << 16;
  return v.f;
}
// async global->LDS, 16B per lane; LDS dest = wave-uniform base + lane*16
__device__ __forceinline__ void gload16(const unsigned short* g, unsigned short* l){
  __builtin_amdgcn_global_load_lds((const __attribute__((address_space(1))) void*)g,
                                   (__attribute__((address_space(3))) void*)l, 16, 0, 0);
}

// ---------------- W transpose + bf16 convert: W[l][k][n] fp32 -> Wt[l][n][k] bf16
__global__ void wt_kernel(const float* __restrict__ W, unsigned short* __restrict__ Wt){
  __shared__ float tile[32][33];
  int l = blockIdx.z;
  int n0 = blockIdx.x * 32, k0 = blockIdx.y * 32;
  int tx = threadIdx.x, ty = threadIdx.y; // (32,8)
  const float* Wl = W + (size_t)l * HH * NN;
  for (int r = 0; r < 4; r++)
    tile[ty + r*8][tx] = Wl[(size_t)(k0 + ty + r*8) * NN + n0 + tx];
  __syncthreads();
  unsigned short* Wtl = Wt + (size_t)l * NN * HH;
  for (int r = 0; r < 4; r++){
    int n = n0 + ty + r*8;
    Wtl[(size_t)n * HH + k0 + tx] = f2bf(tile[tx][ty + r*8]);
  }
}

// ---------------- x fp32 -> bf16 (layer 0 GEMM input)
__global__ void xconv_kernel(const float* __restrict__ x, unsigned short* __restrict__ xb){
  int i = blockIdx.x * blockDim.x + threadIdx.x;
  float4 v = ((const float4*)x)[i];
  ushort4 o;
  o.x = f2bf(v.x); o.y = f2bf(v.y); o.z = f2bf(v.z); o.w = f2bf(v.w);
  *(ushort4*)(xb + (size_t)i * 4) = o;
}

// ---------------- GEMM (R6 K-loop, frozen) + R11: XCD-aware block remap
// (per-XCD 8-row bm band, bn-major => xb band resident in XCD L2) and
// __launch_bounds__(256,3) to allow 3 co-resident blocks/CU.
#define BM 128
#define BN 128
#define BK 64

__global__ __launch_bounds__(256, 3) void gemm_kernel(
    const unsigned short* __restrict__ xb,
    const unsigned short* __restrict__ wt,
    unsigned short* __restrict__ hout,
    const float* __restrict__ a_srcl,
    const float* __restrict__ a_dstl,
    float* __restrict__ psrc,     // [BT][NHEADS][NBLK]
    float* __restrict__ pdst){
  __shared__ __align__(16) unsigned short xs[BM][BK];   // 16 KB
  __shared__ __align__(16) unsigned short wsd[BN][BK];  // 16 KB
  // XCD-aware remap: hw assigns XCD = blockIdx % 8 (round-robin). Give each
  // XCD a contiguous 8-row bm band; iterate bn-major within the band so the
  // xb band (1.6 MB) stays L2-resident and wt slices (0.2 MB) stream through.
  int id = blockIdx.x;              // 1536
  int xcd = id & 7;
  int s = id >> 3;                  // 0..191
  int bn_i = s / 8;                 // 0..23
  int bm_i = (s & 7) + xcd * 8;     // 0..63
  int bm = bm_i * BM;
  int bn = bn_i * BN;
  int tid = threadIdx.x;
  int wave = tid >> 6, lane = tid & 63;
  int m16 = lane & 15, q = lane >> 4;
  int wm = (wave >> 1) * 64, wn = (wave & 1) * 64;
  int r8 = lane >> 3, c8 = lane & 7;
  int cg = (c8 ^ r8) * 8;     // fetched chunk: position c8 holds global chunk c8^(row&7)
  const unsigned short* ga[4]; const unsigned short* gb[4];
  unsigned short* la[4]; unsigned short* lb[4];
  #pragma unroll
  for (int ss = 0; ss < 4; ss++){
    int row = wave * 32 + ss * 8;
    ga[ss] = xb + (size_t)(bm + row + r8) * HH + cg;
    gb[ss] = wt + (size_t)(bn + row + r8) * HH + cg;
    la[ss] = &xs[row][0];
    lb[ss] = &wsd[row][0];
  }
  int rd0 = ((0 + q) ^ (m16 & 7)) * 8;   // ks=0 fragment chunk offset
  int rd1 = ((4 + q) ^ (m16 & 7)) * 8;   // ks=1
  f32x4 acc[4][4] = {};
  for (int k0 = 0; k0 < HH; k0 += BK){
    #pragma unroll
    for (int ss = 0; ss < 4; ss++){
      gload16(ga[ss] + k0, la[ss]);
      gload16(gb[ss] + k0, lb[ss]);
    }
    __syncthreads();
    bf16x8 af[4], bfr[4];
    for (int i = 0; i < 4; i++)
      af[i] = __builtin_bit_cast(bf16x8, *(const uint4*)(&xs[wm + i*16 + m16][rd0]));
    for (int j = 0; j < 4; j++)
      bfr[j] = __builtin_bit_cast(bf16x8, *(const uint4*)(&wsd[wn + j*16 + m16][rd0]));
    for (int i = 0; i < 4; i++)
      for (int j = 0; j < 4; j++)
        acc[i][j] = __builtin_amdgcn_mfma_f32_16x16x32_bf16(af[i], bfr[j], acc[i][j], 0, 0, 0);
    for (int i = 0; i < 4; i++)
      af[i] = __builtin_bit_cast(bf16x8, *(const uint4*)(&xs[wm + i*16 + m16][rd1]));
    for (int j = 0; j < 4; j++)
      bfr[j] = __builtin_bit_cast(bf16x8, *(const uint4*)(&wsd[wn + j*16 + m16][rd1]));
    for (int i = 0; i < 4; i++)
      for (int j = 0; j < 4; j++)
        acc[i][j] = __builtin_amdgcn_mfma_f32_16x16x32_bf16(af[i], bfr[j], acc[i][j], 0, 0, 0);
    __syncthreads();
  }
  // C store (bf16)
  for (int i = 0; i < 4; i++){
    int row0 = bm + wm + i*16 + q*4;
    for (int j = 0; j < 4; j++){
      int col = bn + wn + j*16 + m16;
      unsigned short* hp = hout + (size_t)row0 * NN + col;
      hp[0]            = f2bf(acc[i][j][0]);
      hp[NN]           = f2bf(acc[i][j][1]);
      hp[2*(size_t)NN] = f2bf(acc[i][j][2]);
      hp[3*(size_t)NN] = f2bf(acc[i][j][3]);
    }
  }
  // fused asrc/adst partials: wave covers 64 cols = one (head, blk) slot
  int col0 = bn + wn;
  int head = col0 / DD;
  int blk  = (col0 % DD) >> 6;
  float wsrc[4], wdstw[4];
  for (int j = 0; j < 4; j++){
    int n = col0 + j*16 + m16;
    wsrc[j]  = a_srcl[n];
    wdstw[j] = a_dstl[n];
  }
  for (int i = 0; i < 4; i++){
    for (int reg = 0; reg < 4; reg++){
      float ss = 0.f, dd = 0.f;
      for (int j = 0; j < 4; j++){
        float v = acc[i][j][reg];
        ss += v * wsrc[j];
        dd += v * wdstw[j];
      }
      ss += __shfl_xor(ss, 1, 64); dd += __shfl_xor(dd, 1, 64);
      ss += __shfl_xor(ss, 2, 64); dd += __shfl_xor(dd, 2, 64);
      ss += __shfl_xor(ss, 4, 64); dd += __shfl_xor(dd, 4, 64);
      ss += __shfl_xor(ss, 8, 64); dd += __shfl_xor(dd, 8, 64);
      if (m16 == 0){
        int row = bm + wm + i*16 + q*4 + reg;
        size_t slot = (size_t)row * (NHEADS * NBLK) + head * NBLK + blk;
        psrc[slot] = ss;
        pdst[slot] = dd;
      }
    }
  }
}

// ---------------- attention + head-mean + bias + residual + layernorm
// R10 structure; R11: hs-independent global loads (residual, bias, gamma,
// beta) hoisted before the DMA-drain barrier to overlap staging latency.
__global__ __launch_bounds__(384) void attn_ln_kernel(const unsigned short* __restrict__ h,
    const float* __restrict__ psrc, const float* __restrict__ pdst,
    const float* __restrict__ xin_f32,          // non-null => layer 0 residual (fp32)
    const unsigned short* __restrict__ xin_bf,  // else residual from bf16 xb
    const float* __restrict__ bias_l,
    const float* __restrict__ gamma_l, const float* __restrict__ beta_l,
    float* __restrict__ x_out, unsigned short* __restrict__ xb_next,
    int write_f32){
  int bid = blockIdx.x;                       // 2048
  int grp = ((bid & 7) << 8) | (bid >> 3);    // XCD-contiguous groups
  int token0 = grp * ATPB;
  int t0 = token0 & (TT - 1);
  int bseq = token0 >> 11;
  int tid = threadIdx.x;
  int wave = tid >> 6, lane = tid & 63;
  int ti = tid / 96, c = tid % 96;            // token-in-block, 8-elem chunk
  int token = token0 + ti;
  __shared__ __align__(16) unsigned short hs[NROWS][NN];   // 48 KB
  __shared__ float attn_s[ATPB][NHEADS][KNB];
  __shared__ float as_sh[NROWS * NHEADS], ad_sh[NROWS * NHEADS];
  __shared__ float part_s[ATPB * 96], part_q[ATPB * 96];
  __shared__ float mv_mean[ATPB], mv_rstd[ATPB];
  // stage 8 clamped rows via async DMA (issues immediately, drains at barrier)
  #pragma unroll
  for (int j = 0; j < NROWS; j++){
    int g = t0 - 2 + j;
    g = min(max(g, 0), TT - 1);
    const unsigned short* src = h + ((size_t)(bseq * TT + g)) * NN + tid * 8;
    gload16(src, &hs[j][wave * 512]);
  }
  // hoisted hs-independent loads: overlap DMA drain
  float xr[8], bb[8], gr[8], br[8];
  if (xin_f32){
    const float4* p = (const float4*)&xin_f32[(size_t)token * HH + c * 8];
    *(float4*)&xr[0] = p[0]; *(float4*)&xr[4] = p[1];
  } else {
    uint4 u = *(const uint4*)&xin_bf[(size_t)token * HH + c * 8];
    const unsigned short* us = (const unsigned short*)&u;
    #pragma unroll
    for (int e = 0; e < 8; e++) xr[e] = bf2f(us[e]);
  }
  { const float4* p = (const float4*)&bias_l[c * 8];
    *(float4*)&bb[0] = p[0]; *(float4*)&bb[4] = p[1]; }
  { const float4* p = (const float4*)&gamma_l[c * 8];
    *(float4*)&gr[0] = p[0]; *(float4*)&gr[4] = p[1]; }
  { const float4* p = (const float4*)&beta_l[c * 8];
    *(float4*)&br[0] = p[0]; *(float4*)&br[4] = p[1]; }
  // fused srcred: 64 threads sum the halo tokens' partials into LDS
  if (tid < 2 * NROWS * NHEADS){     // 64
    int which = tid >= NROWS * NHEADS;
    int i = tid & (NROWS * NHEADS - 1);
    int lt = i >> 2, head = i & 3;
    int tcl = min(max(t0 - 2 + lt, 0), TT - 1);
    const float* p = (which ? pdst : psrc) +
        ((size_t)(bseq * TT + tcl) * NHEADS + head) * NBLK;
    float4 a = *(const float4*)(p);
    float4 b = *(const float4*)(p + 4);
    float4 d = *(const float4*)(p + 8);
    float s = a.x+a.y+a.z+a.w + b.x+b.y+b.z+b.w + d.x+d.y+d.z+d.w;
    (which ? ad_sh : as_sh)[i] = s;
  }
  __syncthreads();
  if (tid < ATPB * NHEADS){          // 16: per-(token,head) softmax
    int tii = tid >> 2, head = tid & 3;
    int t = t0 + tii;
    float sc[KNB];
    float mx = -3.0e38f;
    float ad = ad_sh[(tii + 2) * NHEADS + head];
    for (int k = 0; k < KNB; k++){
      int tn = t + k - 2;
      if (tn >= 0 && tn < TT){
        float s = as_sh[(tii + k) * NHEADS + head] + ad;
        s = s > 0.f ? s : 0.2f * s;       // leaky_relu 0.2
        sc[k] = s; mx = fmaxf(mx, s);
      } else sc[k] = -3.0e38f;
    }
    float den = 0.f;
    for (int k = 0; k < KNB; k++){
      float e = (sc[k] > -1.0e38f) ? __expf(sc[k] - mx) : 0.f;
      sc[k] = e; den += e;
    }
    float inv = 0.25f / den;              // fold 1/HEADS into attn
    for (int k = 0; k < KNB; k++) attn_s[tii][head][k] = sc[k] * inv;
  }
  __syncthreads();
  float ac[NHEADS][KNB];
  for (int hd = 0; hd < NHEADS; hd++)
    for (int k = 0; k < KNB; k++) ac[hd][k] = attn_s[ti][hd][k];
  float y8[8] = {};
  for (int hd = 0; hd < NHEADS; hd++){
    #pragma unroll
    for (int k = 0; k < KNB; k++){
      bf16x8 v = __builtin_bit_cast(bf16x8, *(const uint4*)(&hs[ti + k][hd * DD + c * 8]));
      float a = ac[hd][k];
      #pragma unroll
      for (int e = 0; e < 8; e++) y8[e] += a * (float)v[e];
    }
  }
  float s = 0.f, sq = 0.f;
  #pragma unroll
  for (int e = 0; e < 8; e++){
    float zz = y8[e] + bb[e] + xr[e];
    y8[e] = zz; s += zz; sq += zz * zz;
  }
  part_s[tid] = s; part_q[tid] = sq;
  __syncthreads();
  if (wave < ATPB){
    float vs = part_s[wave * 96 + lane];
    float vq = part_q[wave * 96 + lane];
    if (lane < 32){
      vs += part_s[wave * 96 + 64 + lane];
      vq += part_q[wave * 96 + 64 + lane];
    }
    for (int off = 32; off > 0; off >>= 1){
      vs += __shfl_xor(vs, off, 64);
      vq += __shfl_xor(vq, off, 64);
    }
    if (lane == 0){
      float mean = vs * (1.f / HH);
      float var = vq * (1.f / HH) - mean * mean;
      mv_mean[wave] = mean;
      mv_rstd[wave] = rsqrtf(var + 1e-5f);
    }
  }
  __syncthreads();
  float mean = mv_mean[ti], rstd = mv_rstd[ti];
  float o[8];
  #pragma unroll
  for (int e = 0; e < 8; e++)
    o[e] = (y8[e] - mean) * rstd * gr[e] + br[e];
  if (write_f32){
    float* xo = &x_out[(size_t)token * HH + c * 8];
    *(float4*)&xo[0] = *(float4*)&o[0];
    *(float4*)&xo[4] = *(float4*)&o[4];
  } else {
    unsigned short o16[8];
    #pragma unroll
    for (int e = 0; e < 8; e++) o16[e] = f2bf(o[e]);
    *(uint4*)(&xb_next[(size_t)token * HH + c * 8]) = *(uint4*)&o16[0];
  }
}

extern "C" void kernel_launch(void* const* d_in, const int* in_sizes, int n_in,
                              void* d_out, int out_size, void* d_ws, size_t ws_size,
                              hipStream_t stream) {
  const float* x     = (const float*)d_in[0];
  const float* W     = (const float*)d_in[1];
  const float* a_src = (const float*)d_in[2];
  const float* a_dst = (const float*)d_in[3];
  const float* bias  = (const float*)d_in[4];
  const float* gamma = (const float*)d_in[5];
  const float* beta  = (const float*)d_in[6];
  float* out = (float*)d_out;

  char* ws = (char*)d_ws;
  size_t off = 0;
  auto alloc = [&](size_t bytes)->char*{
    char* p = ws + off;
    off = (off + bytes + 255) & ~(size_t)255;
    return p;
  };
  unsigned short* wt   = (unsigned short*)alloc((size_t)LL * NN * HH * 2);
  unsigned short* xb   = (unsigned short*)alloc((size_t)BT * HH * 2);
  unsigned short* hbuf = (unsigned short*)alloc((size_t)BT * NN * 2);
  float* psrc  = (float*)alloc((size_t)BT * NHEADS * NBLK * 4);
  float* pdst  = (float*)alloc((size_t)BT * NHEADS * NBLK * 4);

  wt_kernel<<<dim3(NN/32, HH/32, LL), dim3(32, 8), 0, stream>>>(W, wt);
  xconv_kernel<<<(BT * HH / 4) / 256, 256, 0, stream>>>(x, xb);

  for (int l = 0; l < LL; l++){
    gemm_kernel<<<(NN / BN) * (BT / BM), 256, 0, stream>>>(
        xb, wt + (size_t)l * NN * HH, hbuf,
        a_src + (size_t)l * NHEADS * DD, a_dst + (size_t)l * NHEADS * DD,
        psrc, pdst);
    attn_ln_kernel<<<BT / ATPB, 384, 0, stream>>>(hbuf, psrc, pdst,
        (l == 0) ? x : nullptr, xb,
        bias + (size_t)l * DD, gamma + (size_t)l * HH, beta + (size_t)l * HH,
        out, xb, (l == LL - 1) ? 1 : 0);
  }
}